// Round 2
// baseline (4349.892 us; speedup 1.0000x reference)
//
#include <hip/hip_runtime.h>
#include <hip/hip_bf16.h>
#include <math.h>

typedef __bf16 bf16;
typedef __bf16 bf16x8 __attribute__((ext_vector_type(8)));
typedef __bf16 bf16x4 __attribute__((ext_vector_type(4)));
typedef float  f32x4  __attribute__((ext_vector_type(4)));

#define B_  4
#define N_  1024
#define C_  768
#define H_  12
#define HD_ 64
#define FF_ 3072
#define T_  (B_*N_)      // 4096 tokens
#define D_  12

// ---- async global->LDS, 16B per lane, wave-uniform LDS base ----
__device__ __forceinline__ void gld_lds16(const void* g, void* l) {
    __builtin_amdgcn_global_load_lds(
        (const __attribute__((address_space(1))) void*)g,
        (__attribute__((address_space(3))) void*)l, 16, 0, 0);
}

// =====================================================================
// GEMM:  out[M,N] = A[M,K] @ Bt[N,K]^T + bias
//   A: bf16 activations, Bt: fp32 weights (converted to bf16 at frag read)
// MODE 0: store bf16   MODE 1: GELU(exact) then store bf16
// MODE 2: resid[M,N] (fp32) += result
// 128x128 tile, BK=32, 4 waves 2x2, each wave 64x64 via 4x4 16x16x32 MFMA
// B-tile LDS uses 16B-chunk XOR swizzle (kc ^ (row&7)) to spread banks.
// =====================================================================
template<int MODE>
__global__ __launch_bounds__(256) void gemm_bt(
    const bf16* __restrict__ A, const float* __restrict__ Bt,
    const float* __restrict__ bias, bf16* __restrict__ out,
    float* __restrict__ resid, int M, int N, int K)
{
    __shared__ __align__(16) bf16  lA[128*32];   // 8 KB  [row][k]
    __shared__ __align__(16) float lB[128*32];   // 16 KB [row][kc^swz]
    const int tid  = threadIdx.x;
    const int lane = tid & 63, wave = tid >> 6;
    const int lo = lane & 15, hi = lane >> 4;
    const int wm = wave & 1, wn = wave >> 1;
    const int row0 = blockIdx.x * 128, col0 = blockIdx.y * 128;

    f32x4 acc[4][4];
#pragma unroll
    for (int i = 0; i < 4; i++)
#pragma unroll
        for (int j = 0; j < 4; j++) acc[i][j] = (f32x4){0.f, 0.f, 0.f, 0.f};

    for (int k0 = 0; k0 < K; k0 += 32) {
        // A tile: 512 chunks x 16B (8 bf16). layout [row][32k]
#pragma unroll
        for (int r = 0; r < 2; ++r) {
            const int cb    = r * 256 + wave * 64;   // wave-uniform
            const int chunk = cb + lane;
            const int rw = chunk >> 2, kc = chunk & 3;
            gld_lds16(A + (size_t)(row0 + rw) * K + k0 + kc * 8, lA + cb * 8);
        }
        // B tile: 1024 chunks x 16B (4 fp32). phys slot (rw,kc) holds src
        // chunk kc^(rw&7)  ->  read-time unswizzle spreads bank phases
#pragma unroll
        for (int r = 0; r < 4; ++r) {
            const int cb    = r * 256 + wave * 64;   // wave-uniform
            const int chunk = cb + lane;
            const int rw = chunk >> 3, kc = chunk & 7;
            const int kcs = kc ^ (rw & 7);
            gld_lds16(Bt + (size_t)(col0 + rw) * K + k0 + kcs * 4, lB + cb * 4);
        }
        __syncthreads();
        bf16x8 af[4], bfr[4];
#pragma unroll
        for (int i = 0; i < 4; i++)
            af[i]  = *(const bf16x8*)(lA + (wm * 64 + i * 16 + lo) * 32 + hi * 8);
#pragma unroll
        for (int i = 0; i < 4; i++) {
            const float* base = lB + (wn * 64 + i * 16 + lo) * 32;
            const int sw = lo & 7;
            const f32x4 u0 = *(const f32x4*)(base + (((hi * 2)     ^ sw) * 4));
            const f32x4 u1 = *(const f32x4*)(base + (((hi * 2 + 1) ^ sw) * 4));
            bf16x8 f;
#pragma unroll
            for (int e = 0; e < 4; e++) { f[e] = (bf16)u0[e]; f[4 + e] = (bf16)u1[e]; }
            bfr[i] = f;
        }
#pragma unroll
        for (int mi = 0; mi < 4; mi++)
#pragma unroll
            for (int ni = 0; ni < 4; ni++)
                acc[mi][ni] = __builtin_amdgcn_mfma_f32_16x16x32_bf16(
                    af[mi], bfr[ni], acc[mi][ni], 0, 0, 0);
        __syncthreads();
    }

    // epilogue: C/D layout col=lane&15, row=(lane>>4)*4+reg
#pragma unroll
    for (int mi = 0; mi < 4; mi++) {
#pragma unroll
        for (int ni = 0; ni < 4; ni++) {
            const int gcol = col0 + wn * 64 + ni * 16 + lo;
            const float bv = bias[gcol];
#pragma unroll
            for (int r = 0; r < 4; r++) {
                const int grow = row0 + wm * 64 + mi * 16 + hi * 4 + r;
                float v = acc[mi][ni][r] + bv;
                if (MODE == 1) v = 0.5f * v * (1.0f + erff(v * 0.70710678118f));
                if (MODE == 2) {
                    resid[(size_t)grow * N + gcol] += v;
                } else {
                    out[(size_t)grow * N + gcol] = (bf16)v;
                }
            }
        }
    }
}

// =====================================================================
// LayerNorm: fp32 in [T,768] -> OutT out [T,768]; one wave per token
// =====================================================================
template<typename OutT>
__global__ __launch_bounds__(256) void ln_k(
    const float* __restrict__ x, const float* __restrict__ g,
    const float* __restrict__ b, OutT* __restrict__ out)
{
    const int wave = threadIdx.x >> 6, lane = threadIdx.x & 63;
    const int t = blockIdx.x * 4 + wave;
    const float* row = x + (size_t)t * C_;
    f32x4 v[3];
    float s = 0.f, ss = 0.f;
#pragma unroll
    for (int j = 0; j < 3; j++) {
        v[j] = *(const f32x4*)(row + (j * 64 + lane) * 4);
#pragma unroll
        for (int e = 0; e < 4; e++) { s += v[j][e]; ss += v[j][e] * v[j][e]; }
    }
#pragma unroll
    for (int off = 32; off > 0; off >>= 1) {
        s  += __shfl_xor(s, off);
        ss += __shfl_xor(ss, off);
    }
    const float mu  = s * (1.f / 768.f);
    const float var = ss * (1.f / 768.f) - mu * mu;
    const float rs  = rsqrtf(var + 1e-5f);
    OutT* orow = out + (size_t)t * C_;
#pragma unroll
    for (int j = 0; j < 3; j++) {
        const f32x4 gv = *(const f32x4*)(g + (j * 64 + lane) * 4);
        const f32x4 bv = *(const f32x4*)(b + (j * 64 + lane) * 4);
#pragma unroll
        for (int e = 0; e < 4; e++)
            orow[(j * 64 + lane) * 4 + e] = (OutT)((v[j][e] - mu) * rs * gv[e] + bv[e]);
    }
}

// =====================================================================
// x + pos_x (fp32) -> fp32 residual stream
// =====================================================================
__global__ __launch_bounds__(256) void addpos_k(
    const float* __restrict__ x, const float* __restrict__ p, float* __restrict__ o)
{
    const int i = (blockIdx.x * 256 + threadIdx.x) * 4;
    const f32x4 xv = *(const f32x4*)(x + i);
    const f32x4 pv = *(const f32x4*)(p + i);
    f32x4 ov;
#pragma unroll
    for (int e = 0; e < 4; e++) ov[e] = xv[e] + pv[e];
    *(f32x4*)(o + i) = ov;
}

// =====================================================================
// Flash attention: qkv bf16 [4096, 2304] -> out bf16 [4096, 768]
// block = (qtile of 64 rows, b*H+h); 4 waves, wave w owns q rows w*16..+16
// online softmax; P converts C-layout -> A-layout via per-wave LDS
// =====================================================================
__global__ __launch_bounds__(256) void attn_k(
    const bf16* __restrict__ qkv, bf16* __restrict__ out)
{
    const int qt = blockIdx.x;          // 0..15
    const int bh = blockIdx.y;          // 0..47
    const int b = bh / H_, h = bh % H_;
    const int lane = threadIdx.x & 63, wave = threadIdx.x >> 6;
    const int lo = lane & 15, hi = lane >> 4;

    __shared__ __align__(16) bf16 lK[64 * 64];        // [key][d]
    __shared__ __align__(16) bf16 lV[64 * 64];        // transposed [d][key]
    __shared__ __align__(16) bf16 lP[4][16 * 64];     // per-wave P tile [q][key]

    const size_t tokbase = (size_t)b * N_;

    // persistent Q A-fragments: m=lo (q row), k = hi*8+j (+32 for qf1)
    const bf16* qptr = qkv + (tokbase + qt * 64 + wave * 16 + lo) * (3 * C_) + h * HD_;
    const bf16x8 qf0 = *(const bf16x8*)(qptr + hi * 8);
    const bf16x8 qf1 = *(const bf16x8*)(qptr + 32 + hi * 8);

    float m_r[4], l_r[4];
    f32x4 oacc[4];
#pragma unroll
    for (int r = 0; r < 4; r++) { m_r[r] = -1e30f; l_r[r] = 0.f; }
#pragma unroll
    for (int di = 0; di < 4; di++) oacc[di] = (f32x4){0.f, 0.f, 0.f, 0.f};

    for (int kt = 0; kt < 16; ++kt) {
        const int kb0 = kt * 64;
        // ---- stage K [key][d] and V^T [d][key] ----
#pragma unroll
        for (int r = 0; r < 2; ++r) {
            const int chunk = r * 256 + threadIdx.x;     // 0..511
            const int key = chunk >> 3, dc = chunk & 7;
            const bf16* kp = qkv + (tokbase + kb0 + key) * (3 * C_) + C_ + h * HD_ + dc * 8;
            *(bf16x8*)(lK + key * 64 + dc * 8) = *(const bf16x8*)kp;
            const bf16* vp = qkv + (tokbase + kb0 + key) * (3 * C_) + 2 * C_ + h * HD_ + dc * 8;
            const bf16x8 vv = *(const bf16x8*)vp;
#pragma unroll
            for (int j = 0; j < 8; j++) lV[(dc * 8 + j) * 64 + key] = vv[j];
        }
        __syncthreads();

        // ---- S = Q @ K^T (per wave: 16 q x 64 keys) ----
        f32x4 sacc[4];
#pragma unroll
        for (int kb = 0; kb < 4; kb++) {
            const bf16x8 b0 = *(const bf16x8*)(lK + (kb * 16 + lo) * 64 + hi * 8);
            const bf16x8 b1 = *(const bf16x8*)(lK + (kb * 16 + lo) * 64 + 32 + hi * 8);
            f32x4 a = (f32x4){0.f, 0.f, 0.f, 0.f};
            a = __builtin_amdgcn_mfma_f32_16x16x32_bf16(qf0, b0, a, 0, 0, 0);
            a = __builtin_amdgcn_mfma_f32_16x16x32_bf16(qf1, b1, a, 0, 0, 0);
            sacc[kb] = a;
        }

        // ---- online softmax (row r of wave = q row hi*4+r; reduce over lo) ----
        float tm[4], mn[4], alpha[4], ts[4], ps[4][4];
#pragma unroll
        for (int r = 0; r < 4; r++) {
            tm[r] = fmaxf(fmaxf(sacc[0][r], sacc[1][r]),
                          fmaxf(sacc[2][r], sacc[3][r])) * 0.125f;
#pragma unroll
            for (int off = 1; off < 16; off <<= 1)
                tm[r] = fmaxf(tm[r], __shfl_xor(tm[r], off));
            mn[r] = fmaxf(m_r[r], tm[r]);
            alpha[r] = __expf(m_r[r] - mn[r]);
            ts[r] = 0.f;
        }
#pragma unroll
        for (int kb = 0; kb < 4; kb++)
#pragma unroll
            for (int r = 0; r < 4; r++) {
                const float p = __expf(sacc[kb][r] * 0.125f - mn[r]);
                ps[kb][r] = p;
                ts[r] += p;
            }
#pragma unroll
        for (int r = 0; r < 4; r++) {
#pragma unroll
            for (int off = 1; off < 16; off <<= 1)
                ts[r] += __shfl_xor(ts[r], off);
            l_r[r] = l_r[r] * alpha[r] + ts[r];
            m_r[r] = mn[r];
        }
#pragma unroll
        for (int di = 0; di < 4; di++)
#pragma unroll
            for (int r = 0; r < 4; r++) oacc[di][r] *= alpha[r];

        // ---- P: C-layout -> LDS -> A-layout ----
#pragma unroll
        for (int kb = 0; kb < 4; kb++)
#pragma unroll
            for (int r = 0; r < 4; r++)
                lP[wave][(hi * 4 + r) * 64 + kb * 16 + lo] = (bf16)ps[kb][r];
        __syncthreads();

        const bf16x8 pa0 = *(const bf16x8*)(&lP[wave][lo * 64 + hi * 8]);
        const bf16x8 pa1 = *(const bf16x8*)(&lP[wave][lo * 64 + 32 + hi * 8]);
#pragma unroll
        for (int di = 0; di < 4; di++) {
            const bf16x8 v0 = *(const bf16x8*)(lV + (di * 16 + lo) * 64 + hi * 8);
            const bf16x8 v1 = *(const bf16x8*)(lV + (di * 16 + lo) * 64 + 32 + hi * 8);
            oacc[di] = __builtin_amdgcn_mfma_f32_16x16x32_bf16(pa0, v0, oacc[di], 0, 0, 0);
            oacc[di] = __builtin_amdgcn_mfma_f32_16x16x32_bf16(pa1, v1, oacc[di], 0, 0, 0);
        }
        __syncthreads();
    }

    // ---- epilogue: O / l ----
#pragma unroll
    for (int di = 0; di < 4; di++)
#pragma unroll
        for (int r = 0; r < 4; r++) {
            const size_t tok = tokbase + qt * 64 + wave * 16 + hi * 4 + r;
            out[tok * C_ + h * HD_ + di * 16 + lo] = (bf16)(oacc[di][r] / l_r[r]);
        }
}

// =====================================================================
extern "C" void kernel_launch(void* const* d_in, const int* in_sizes, int n_in,
                              void* d_out, int out_size, void* d_ws, size_t ws_size,
                              hipStream_t stream)
{
    const float* x      = (const float*)d_in[0];
    const float* pos_x  = (const float*)d_in[1];
    const float* qkv_w  = (const float*)d_in[2];
    const float* qkv_b  = (const float*)d_in[3];
    const float* proj_w = (const float*)d_in[4];
    const float* proj_b = (const float*)d_in[5];
    const float* fc1_w  = (const float*)d_in[6];
    const float* fc1_b  = (const float*)d_in[7];
    const float* fc2_w  = (const float*)d_in[8];
    const float* fc2_b  = (const float*)d_in[9];
    const float* ln1_g  = (const float*)d_in[10];
    const float* ln1_b  = (const float*)d_in[11];
    const float* ln2_g  = (const float*)d_in[12];
    const float* ln2_b  = (const float*)d_in[13];
    const float* nf_g   = (const float*)d_in[14];
    const float* nf_b   = (const float*)d_in[15];

    char* ws = (char*)d_ws;
    float* xres  = (float*)(ws);                         // 4096*768 fp32 = 12582912 B
    bf16* hbuf   = (bf16*)(ws + 12582912);               // 4096*768  bf16
    bf16* qkvbuf = (bf16*)(ws + 18874368);               // 4096*2304 bf16
    bf16* attno  = (bf16*)(ws + 37748736);               // 4096*768  bf16
    bf16* hid    = (bf16*)(ws + 44040192);               // 4096*3072 bf16  (end 69206016)

    addpos_k<<<T_ * C_ / 4 / 256, 256, 0, stream>>>(x, pos_x, xres);

    for (int L = 0; L < D_; ++L) {
        ln_k<bf16><<<T_ / 4, 256, 0, stream>>>(xres, ln1_g + L * C_, ln1_b + L * C_, hbuf);
        gemm_bt<0><<<dim3(T_ / 128, (3 * C_) / 128), 256, 0, stream>>>(
            hbuf, qkv_w + (size_t)L * 3 * C_ * C_, qkv_b + (size_t)L * 3 * C_,
            qkvbuf, nullptr, T_, 3 * C_, C_);
        attn_k<<<dim3(N_ / 64, B_ * H_), 256, 0, stream>>>(qkvbuf, attno);
        gemm_bt<2><<<dim3(T_ / 128, C_ / 128), 256, 0, stream>>>(
            attno, proj_w + (size_t)L * C_ * C_, proj_b + (size_t)L * C_,
            nullptr, xres, T_, C_, C_);
        ln_k<bf16><<<T_ / 4, 256, 0, stream>>>(xres, ln2_g + L * C_, ln2_b + L * C_, hbuf);
        gemm_bt<1><<<dim3(T_ / 128, FF_ / 128), 256, 0, stream>>>(
            hbuf, fc1_w + (size_t)L * FF_ * C_, fc1_b + (size_t)L * FF_,
            hid, nullptr, T_, FF_, C_);
        gemm_bt<2><<<dim3(T_ / 128, C_ / 128), 256, 0, stream>>>(
            hid, fc2_w + (size_t)L * C_ * FF_, fc2_b + (size_t)L * C_,
            nullptr, xres, T_, C_, FF_);
    }
    ln_k<float><<<T_ / 4, 256, 0, stream>>>(xres, nf_g, nf_b, (float*)d_out);
}

// Round 3
// 3283.709 us; speedup vs baseline: 1.3247x; 1.3247x over previous
//
#include <hip/hip_runtime.h>
#include <hip/hip_bf16.h>
#include <math.h>

typedef __bf16 bf16;
typedef __bf16 bf16x8 __attribute__((ext_vector_type(8)));
typedef __bf16 bf16x4 __attribute__((ext_vector_type(4)));
typedef float  f32x4  __attribute__((ext_vector_type(4)));

#define B_  4
#define N_  1024
#define C_  768
#define H_  12
#define HD_ 64
#define FF_ 3072
#define T_  (B_*N_)      // 4096 tokens
#define D_  12

// ---- async global->LDS, 16B per lane, wave-uniform LDS base ----
__device__ __forceinline__ void gld_lds16(const void* g, void* l) {
    __builtin_amdgcn_global_load_lds(
        (const __attribute__((address_space(1))) void*)g,
        (__attribute__((address_space(3))) void*)l, 16, 0, 0);
}

// =====================================================================
// GEMM:  out[M,N] = A[M,K] @ Bt[N,K]^T + bias
//   A: bf16 activations. WT = bf16 (preconverted weights, m97 structure)
//   or float (fallback: swizzled fp32 staging + in-loop cvt).
// MODE 0: store bf16   MODE 1: GELU(exact) then store bf16
// MODE 2: resid[M,N] (fp32) atomicAdd (split-K safe; bias only on z==0)
// 128x128 tile, BK=32, 4 waves 2x2, each wave 64x64 via 4x4 16x16x32 MFMA
// gridDim.z = split-K count; each z handles Ks of the K dim.
// =====================================================================
template<typename WT, int MODE>
__global__ __launch_bounds__(256) void gemm_bt(
    const bf16* __restrict__ A, const WT* __restrict__ Bt,
    const float* __restrict__ bias, bf16* __restrict__ out,
    float* __restrict__ resid, int M, int N, int Kfull, int Ks)
{
    __shared__ __align__(16) bf16 lA[128*32];   // 8 KB  [row][k]
    __shared__ __align__(16) WT   lB[128*32];   // 8 KB bf16 / 16 KB f32
    const int tid  = threadIdx.x;
    const int lane = tid & 63, wave = tid >> 6;
    const int lo = lane & 15, hi = lane >> 4;
    const int wm = wave & 1, wn = wave >> 1;
    const int row0 = blockIdx.x * 128, col0 = blockIdx.y * 128;
    const int k0base = blockIdx.z * Ks;

    f32x4 acc[4][4];
#pragma unroll
    for (int i = 0; i < 4; i++)
#pragma unroll
        for (int j = 0; j < 4; j++) acc[i][j] = (f32x4){0.f, 0.f, 0.f, 0.f};

    for (int k0 = k0base; k0 < k0base + Ks; k0 += 32) {
        // A tile: 512 chunks x 16B (8 bf16), layout [row][32k]
#pragma unroll
        for (int r = 0; r < 2; ++r) {
            const int cb    = r * 256 + wave * 64;   // wave-uniform base
            const int chunk = cb + lane;
            const int rw = chunk >> 2, kc = chunk & 3;
            gld_lds16(A + (size_t)(row0 + rw) * Kfull + k0 + kc * 8, lA + cb * 8);
        }
        if constexpr (sizeof(WT) == 2) {
            // B tile bf16: identical structure to A
#pragma unroll
            for (int r = 0; r < 2; ++r) {
                const int cb    = r * 256 + wave * 64;
                const int chunk = cb + lane;
                const int rw = chunk >> 2, kc = chunk & 3;
                gld_lds16(Bt + (size_t)(col0 + rw) * Kfull + k0 + kc * 8,
                          (bf16*)lB + cb * 8);
            }
        } else {
            // B tile fp32: 1024 chunks x 16B, XOR-swizzled (kc ^ (row&7))
#pragma unroll
            for (int r = 0; r < 4; ++r) {
                const int cb    = r * 256 + wave * 64;
                const int chunk = cb + lane;
                const int rw = chunk >> 3, kc = chunk & 7;
                const int kcs = kc ^ (rw & 7);
                gld_lds16(Bt + (size_t)(col0 + rw) * Kfull + k0 + kcs * 4,
                          (float*)lB + cb * 4);
            }
        }
        __syncthreads();
        bf16x8 af[4], bfr[4];
#pragma unroll
        for (int i = 0; i < 4; i++)
            af[i]  = *(const bf16x8*)(lA + (wm * 64 + i * 16 + lo) * 32 + hi * 8);
#pragma unroll
        for (int i = 0; i < 4; i++) {
            if constexpr (sizeof(WT) == 2) {
                bfr[i] = *(const bf16x8*)((const bf16*)lB +
                             (wn * 64 + i * 16 + lo) * 32 + hi * 8);
            } else {
                const float* base = (const float*)lB + (wn * 64 + i * 16 + lo) * 32;
                const int sw = lo & 7;
                const f32x4 u0 = *(const f32x4*)(base + (((hi * 2)     ^ sw) * 4));
                const f32x4 u1 = *(const f32x4*)(base + (((hi * 2 + 1) ^ sw) * 4));
                bf16x8 f;
#pragma unroll
                for (int e = 0; e < 4; e++) { f[e] = (bf16)u0[e]; f[4+e] = (bf16)u1[e]; }
                bfr[i] = f;
            }
        }
#pragma unroll
        for (int mi = 0; mi < 4; mi++)
#pragma unroll
            for (int ni = 0; ni < 4; ni++)
                acc[mi][ni] = __builtin_amdgcn_mfma_f32_16x16x32_bf16(
                    af[mi], bfr[ni], acc[mi][ni], 0, 0, 0);
        __syncthreads();
    }

    // epilogue: C/D layout col=lane&15, row=(lane>>4)*4+reg
    const float bscale = (blockIdx.z == 0) ? 1.0f : 0.0f;
#pragma unroll
    for (int mi = 0; mi < 4; mi++) {
#pragma unroll
        for (int ni = 0; ni < 4; ni++) {
            const int gcol = col0 + wn * 64 + ni * 16 + lo;
            const float bv = bias[gcol] * bscale;
#pragma unroll
            for (int r = 0; r < 4; r++) {
                const int grow = row0 + wm * 64 + mi * 16 + hi * 4 + r;
                float v = acc[mi][ni][r] + bv;
                if (MODE == 1) v = 0.5f * v * (1.0f + erff(v * 0.70710678118f));
                if (MODE == 2) {
                    atomicAdd(&resid[(size_t)grow * N + gcol], v);
                } else {
                    out[(size_t)grow * N + gcol] = (bf16)v;
                }
            }
        }
    }
}

// =====================================================================
// fp32 -> bf16 bulk convert (weights), 8 elems/lane
// =====================================================================
__global__ __launch_bounds__(256) void cvt_k(
    const float* __restrict__ src, bf16* __restrict__ dst)
{
    const int i = (blockIdx.x * 256 + threadIdx.x) * 8;
    const f32x4 a = *(const f32x4*)(src + i);
    const f32x4 b = *(const f32x4*)(src + i + 4);
    bf16x8 o;
#pragma unroll
    for (int e = 0; e < 4; e++) { o[e] = (bf16)a[e]; o[4 + e] = (bf16)b[e]; }
    *(bf16x8*)(dst + i) = o;
}

// =====================================================================
// LayerNorm: fp32 in [T,768] -> OutT out [T,768]; one wave per token
// =====================================================================
template<typename OutT>
__global__ __launch_bounds__(256) void ln_k(
    const float* __restrict__ x, const float* __restrict__ g,
    const float* __restrict__ b, OutT* __restrict__ out)
{
    const int wave = threadIdx.x >> 6, lane = threadIdx.x & 63;
    const int t = blockIdx.x * 4 + wave;
    const float* row = x + (size_t)t * C_;
    f32x4 v[3];
    float s = 0.f, ss = 0.f;
#pragma unroll
    for (int j = 0; j < 3; j++) {
        v[j] = *(const f32x4*)(row + (j * 64 + lane) * 4);
#pragma unroll
        for (int e = 0; e < 4; e++) { s += v[j][e]; ss += v[j][e] * v[j][e]; }
    }
#pragma unroll
    for (int off = 32; off > 0; off >>= 1) {
        s  += __shfl_xor(s, off);
        ss += __shfl_xor(ss, off);
    }
    const float mu  = s * (1.f / 768.f);
    const float var = ss * (1.f / 768.f) - mu * mu;
    const float rs  = rsqrtf(var + 1e-5f);
    OutT* orow = out + (size_t)t * C_;
#pragma unroll
    for (int j = 0; j < 3; j++) {
        const f32x4 gv = *(const f32x4*)(g + (j * 64 + lane) * 4);
        const f32x4 bv = *(const f32x4*)(b + (j * 64 + lane) * 4);
#pragma unroll
        for (int e = 0; e < 4; e++)
            orow[(j * 64 + lane) * 4 + e] = (OutT)((v[j][e] - mu) * rs * gv[e] + bv[e]);
    }
}

// =====================================================================
// x + pos_x (fp32) -> fp32 residual stream
// =====================================================================
__global__ __launch_bounds__(256) void addpos_k(
    const float* __restrict__ x, const float* __restrict__ p, float* __restrict__ o)
{
    const int i = (blockIdx.x * 256 + threadIdx.x) * 4;
    const f32x4 xv = *(const f32x4*)(x + i);
    const f32x4 pv = *(const f32x4*)(p + i);
    f32x4 ov;
#pragma unroll
    for (int e = 0; e < 4; e++) ov[e] = xv[e] + pv[e];
    *(f32x4*)(o + i) = ov;
}

// =====================================================================
// Flash attention: qkv bf16 [4096, 2304] -> out bf16 [4096, 768]
// block = (qtile of 64 rows, b*H+h); 4 waves, wave w owns q rows w*16..+16
// online softmax; P converts C-layout -> A-layout via per-wave LDS
// =====================================================================
__global__ __launch_bounds__(256) void attn_k(
    const bf16* __restrict__ qkv, bf16* __restrict__ out)
{
    const int qt = blockIdx.x;          // 0..15
    const int bh = blockIdx.y;          // 0..47
    const int b = bh / H_, h = bh % H_;
    const int lane = threadIdx.x & 63, wave = threadIdx.x >> 6;
    const int lo = lane & 15, hi = lane >> 4;

    __shared__ __align__(16) bf16 lK[64 * 64];        // [key][d]
    __shared__ __align__(16) bf16 lV[64 * 64];        // transposed [d][key]
    __shared__ __align__(16) bf16 lP[4][16 * 64];     // per-wave P tile [q][key]

    const size_t tokbase = (size_t)b * N_;

    // persistent Q A-fragments: m=lo (q row), k = hi*8+j (+32 for qf1)
    const bf16* qptr = qkv + (tokbase + qt * 64 + wave * 16 + lo) * (3 * C_) + h * HD_;
    const bf16x8 qf0 = *(const bf16x8*)(qptr + hi * 8);
    const bf16x8 qf1 = *(const bf16x8*)(qptr + 32 + hi * 8);

    float m_r[4], l_r[4];
    f32x4 oacc[4];
#pragma unroll
    for (int r = 0; r < 4; r++) { m_r[r] = -1e30f; l_r[r] = 0.f; }
#pragma unroll
    for (int di = 0; di < 4; di++) oacc[di] = (f32x4){0.f, 0.f, 0.f, 0.f};

    for (int kt = 0; kt < 16; ++kt) {
        const int kb0 = kt * 64;
        // ---- stage K [key][d] and V^T [d][key] ----
#pragma unroll
        for (int r = 0; r < 2; ++r) {
            const int chunk = r * 256 + threadIdx.x;     // 0..511
            const int key = chunk >> 3, dc = chunk & 7;
            const bf16* kp = qkv + (tokbase + kb0 + key) * (3 * C_) + C_ + h * HD_ + dc * 8;
            *(bf16x8*)(lK + key * 64 + dc * 8) = *(const bf16x8*)kp;
            const bf16* vp = qkv + (tokbase + kb0 + key) * (3 * C_) + 2 * C_ + h * HD_ + dc * 8;
            const bf16x8 vv = *(const bf16x8*)vp;
#pragma unroll
            for (int j = 0; j < 8; j++) lV[(dc * 8 + j) * 64 + key] = vv[j];
        }
        __syncthreads();

        // ---- S = Q @ K^T (per wave: 16 q x 64 keys) ----
        f32x4 sacc[4];
#pragma unroll
        for (int kb = 0; kb < 4; kb++) {
            const bf16x8 b0 = *(const bf16x8*)(lK + (kb * 16 + lo) * 64 + hi * 8);
            const bf16x8 b1 = *(const bf16x8*)(lK + (kb * 16 + lo) * 64 + 32 + hi * 8);
            f32x4 a = (f32x4){0.f, 0.f, 0.f, 0.f};
            a = __builtin_amdgcn_mfma_f32_16x16x32_bf16(qf0, b0, a, 0, 0, 0);
            a = __builtin_amdgcn_mfma_f32_16x16x32_bf16(qf1, b1, a, 0, 0, 0);
            sacc[kb] = a;
        }

        // ---- online softmax (row r = q row hi*4+r; reduce over lo lanes) ----
        float tm[4], mn[4], alpha[4], ts[4], ps[4][4];
#pragma unroll
        for (int r = 0; r < 4; r++) {
            tm[r] = fmaxf(fmaxf(sacc[0][r], sacc[1][r]),
                          fmaxf(sacc[2][r], sacc[3][r])) * 0.125f;
#pragma unroll
            for (int off = 1; off < 16; off <<= 1)
                tm[r] = fmaxf(tm[r], __shfl_xor(tm[r], off));
            mn[r] = fmaxf(m_r[r], tm[r]);
            alpha[r] = __expf(m_r[r] - mn[r]);
            ts[r] = 0.f;
        }
#pragma unroll
        for (int kb = 0; kb < 4; kb++)
#pragma unroll
            for (int r = 0; r < 4; r++) {
                const float p = __expf(sacc[kb][r] * 0.125f - mn[r]);
                ps[kb][r] = p;
                ts[r] += p;
            }
#pragma unroll
        for (int r = 0; r < 4; r++) {
#pragma unroll
            for (int off = 1; off < 16; off <<= 1)
                ts[r] += __shfl_xor(ts[r], off);
            l_r[r] = l_r[r] * alpha[r] + ts[r];
            m_r[r] = mn[r];
        }
#pragma unroll
        for (int di = 0; di < 4; di++)
#pragma unroll
            for (int r = 0; r < 4; r++) oacc[di][r] *= alpha[r];

        // ---- P: C-layout -> LDS -> A-layout ----
#pragma unroll
        for (int kb = 0; kb < 4; kb++)
#pragma unroll
            for (int r = 0; r < 4; r++)
                lP[wave][(hi * 4 + r) * 64 + kb * 16 + lo] = (bf16)ps[kb][r];
        __syncthreads();

        const bf16x8 pa0 = *(const bf16x8*)(&lP[wave][lo * 64 + hi * 8]);
        const bf16x8 pa1 = *(const bf16x8*)(&lP[wave][lo * 64 + 32 + hi * 8]);
#pragma unroll
        for (int di = 0; di < 4; di++) {
            const bf16x8 v0 = *(const bf16x8*)(lV + (di * 16 + lo) * 64 + hi * 8);
            const bf16x8 v1 = *(const bf16x8*)(lV + (di * 16 + lo) * 64 + 32 + hi * 8);
            oacc[di] = __builtin_amdgcn_mfma_f32_16x16x32_bf16(pa0, v0, oacc[di], 0, 0, 0);
            oacc[di] = __builtin_amdgcn_mfma_f32_16x16x32_bf16(pa1, v1, oacc[di], 0, 0, 0);
        }
        __syncthreads();
    }

    // ---- epilogue: O / l ----
#pragma unroll
    for (int di = 0; di < 4; di++)
#pragma unroll
        for (int r = 0; r < 4; r++) {
            const size_t tok = tokbase + qt * 64 + wave * 16 + hi * 4 + r;
            out[tok * C_ + h * HD_ + di * 16 + lo] = (bf16)(oacc[di][r] / l_r[r]);
        }
}

// =====================================================================
extern "C" void kernel_launch(void* const* d_in, const int* in_sizes, int n_in,
                              void* d_out, int out_size, void* d_ws, size_t ws_size,
                              hipStream_t stream)
{
    const float* x      = (const float*)d_in[0];
    const float* pos_x  = (const float*)d_in[1];
    const float* qkv_w  = (const float*)d_in[2];
    const float* qkv_b  = (const float*)d_in[3];
    const float* proj_w = (const float*)d_in[4];
    const float* proj_b = (const float*)d_in[5];
    const float* fc1_w  = (const float*)d_in[6];
    const float* fc1_b  = (const float*)d_in[7];
    const float* fc2_w  = (const float*)d_in[8];
    const float* fc2_b  = (const float*)d_in[9];
    const float* ln1_g  = (const float*)d_in[10];
    const float* ln1_b  = (const float*)d_in[11];
    const float* ln2_g  = (const float*)d_in[12];
    const float* ln2_b  = (const float*)d_in[13];
    const float* nf_g   = (const float*)d_in[14];
    const float* nf_b   = (const float*)d_in[15];

    char* ws = (char*)d_ws;
    float* xres  = (float*)(ws);                         // 12,582,912 B
    bf16* hbuf   = (bf16*)(ws + 12582912);               //  6,291,456
    bf16* qkvbuf = (bf16*)(ws + 18874368);               // 18,874,368
    bf16* attno  = (bf16*)(ws + 37748736);               //  6,291,456
    bf16* hid    = (bf16*)(ws + 44040192);               // 25,165,824 (end 69,206,016)
    bf16* wq     = (bf16*)(ws + 69206016);               // 42,467,328
    bf16* wp     = (bf16*)(ws + 111673344);              // 14,155,776
    bf16* w1     = (bf16*)(ws + 125829120);              // 56,623,104
    bf16* w2     = (bf16*)(ws + 182452224);              // 56,623,104 (end 239,075,328)
    const bool usebf16 = ws_size >= (size_t)239075328;

    addpos_k<<<T_ * C_ / 4 / 256, 256, 0, stream>>>(x, pos_x, xres);

    if (usebf16) {
        cvt_k<<<D_ * 3 * C_ * C_ / 2048, 256, 0, stream>>>(qkv_w, wq);
        cvt_k<<<D_ * C_ * C_ / 2048, 256, 0, stream>>>(proj_w, wp);
        cvt_k<<<D_ * FF_ * C_ / 2048, 256, 0, stream>>>(fc1_w, w1);
        cvt_k<<<D_ * C_ * FF_ / 2048, 256, 0, stream>>>(fc2_w, w2);
    }

    for (int L = 0; L < D_; ++L) {
        ln_k<bf16><<<T_ / 4, 256, 0, stream>>>(xres, ln1_g + L * C_, ln1_b + L * C_, hbuf);
        if (usebf16) {
            gemm_bt<bf16,0><<<dim3(T_/128, (3*C_)/128, 1), 256, 0, stream>>>(
                hbuf, wq + (size_t)L * 3 * C_ * C_, qkv_b + (size_t)L * 3 * C_,
                qkvbuf, nullptr, T_, 3 * C_, C_, C_);
        } else {
            gemm_bt<float,0><<<dim3(T_/128, (3*C_)/128, 1), 256, 0, stream>>>(
                hbuf, qkv_w + (size_t)L * 3 * C_ * C_, qkv_b + (size_t)L * 3 * C_,
                qkvbuf, nullptr, T_, 3 * C_, C_, C_);
        }
        attn_k<<<dim3(N_ / 64, B_ * H_), 256, 0, stream>>>(qkvbuf, attno);
        if (usebf16) {
            gemm_bt<bf16,2><<<dim3(T_/128, C_/128, 2), 256, 0, stream>>>(
                attno, wp + (size_t)L * C_ * C_, proj_b + (size_t)L * C_,
                nullptr, xres, T_, C_, C_, C_ / 2);
        } else {
            gemm_bt<float,2><<<dim3(T_/128, C_/128, 2), 256, 0, stream>>>(
                attno, proj_w + (size_t)L * C_ * C_, proj_b + (size_t)L * C_,
                nullptr, xres, T_, C_, C_, C_ / 2);
        }
        ln_k<bf16><<<T_ / 4, 256, 0, stream>>>(xres, ln2_g + L * C_, ln2_b + L * C_, hbuf);
        if (usebf16) {
            gemm_bt<bf16,1><<<dim3(T_/128, FF_/128, 1), 256, 0, stream>>>(
                hbuf, w1 + (size_t)L * FF_ * C_, fc1_b + (size_t)L * FF_,
                hid, nullptr, T_, FF_, C_, C_);
            gemm_bt<bf16,2><<<dim3(T_/128, C_/128, 2), 256, 0, stream>>>(
                hid, w2 + (size_t)L * C_ * FF_, fc2_b + (size_t)L * C_,
                nullptr, xres, T_, C_, FF_, FF_ / 2);
        } else {
            gemm_bt<float,1><<<dim3(T_/128, FF_/128, 1), 256, 0, stream>>>(
                hbuf, fc1_w + (size_t)L * FF_ * C_, fc1_b + (size_t)L * FF_,
                hid, nullptr, T_, FF_, C_, C_);
            gemm_bt<float,2><<<dim3(T_/128, C_/128, 2), 256, 0, stream>>>(
                hid, fc2_w + (size_t)L * C_ * FF_, fc2_b + (size_t)L * C_,
                nullptr, xres, T_, C_, FF_, FF_ / 2);
        }
    }
    ln_k<float><<<T_ / 4, 256, 0, stream>>>(xres, nf_g, nf_b, (float*)d_out);
}

// Round 4
// 2936.638 us; speedup vs baseline: 1.4812x; 1.1182x over previous
//
#include <hip/hip_runtime.h>
#include <hip/hip_bf16.h>
#include <math.h>

typedef __bf16 bf16;
typedef __bf16 bf16x8 __attribute__((ext_vector_type(8)));
typedef __bf16 bf16x4 __attribute__((ext_vector_type(4)));
typedef float  f32x4  __attribute__((ext_vector_type(4)));

#define B_  4
#define N_  1024
#define C_  768
#define H_  12
#define HD_ 64
#define FF_ 3072
#define T_  (B_*N_)      // 4096 tokens
#define D_  12

// ---- async global->LDS, 16B per lane, wave-uniform LDS base ----
__device__ __forceinline__ void gld_lds16(const void* g, void* l) {
    __builtin_amdgcn_global_load_lds(
        (const __attribute__((address_space(1))) void*)g,
        (__attribute__((address_space(3))) void*)l, 16, 0, 0);
}

// =====================================================================
// GEMM:  out[M,N] = A[M,K] @ Bt[N,K]^T + bias
//   A: bf16 activations. WT = bf16 (preconverted weights, m97 structure)
//   or float (fallback: swizzled fp32 staging + in-loop cvt).
// MODE 0: store bf16   MODE 1: GELU(exact) then store bf16
// MODE 2: resid[M,N] (fp32) atomicAdd (split-K safe; bias only on z==0)
// 128x128 tile, BK=32, 4 waves 2x2, each wave 64x64 via 4x4 16x16x32 MFMA
// =====================================================================
template<typename WT, int MODE>
__global__ __launch_bounds__(256) void gemm_bt(
    const bf16* __restrict__ A, const WT* __restrict__ Bt,
    const float* __restrict__ bias, bf16* __restrict__ out,
    float* __restrict__ resid, int M, int N, int Kfull, int Ks)
{
    __shared__ __align__(16) bf16 lA[128*32];   // 8 KB  [row][k]
    __shared__ __align__(16) WT   lB[128*32];   // 8 KB bf16 / 16 KB f32
    const int tid  = threadIdx.x;
    const int lane = tid & 63, wave = tid >> 6;
    const int lo = lane & 15, hi = lane >> 4;
    const int wm = wave & 1, wn = wave >> 1;
    const int row0 = blockIdx.x * 128, col0 = blockIdx.y * 128;
    const int k0base = blockIdx.z * Ks;

    f32x4 acc[4][4];
#pragma unroll
    for (int i = 0; i < 4; i++)
#pragma unroll
        for (int j = 0; j < 4; j++) acc[i][j] = (f32x4){0.f, 0.f, 0.f, 0.f};

    for (int k0 = k0base; k0 < k0base + Ks; k0 += 32) {
        // A tile: 512 chunks x 16B (8 bf16), layout [row][32k]
#pragma unroll
        for (int r = 0; r < 2; ++r) {
            const int cb    = r * 256 + wave * 64;   // wave-uniform base
            const int chunk = cb + lane;
            const int rw = chunk >> 2, kc = chunk & 3;
            gld_lds16(A + (size_t)(row0 + rw) * Kfull + k0 + kc * 8, lA + cb * 8);
        }
        if constexpr (sizeof(WT) == 2) {
            // B tile bf16: identical structure to A
#pragma unroll
            for (int r = 0; r < 2; ++r) {
                const int cb    = r * 256 + wave * 64;
                const int chunk = cb + lane;
                const int rw = chunk >> 2, kc = chunk & 3;
                gld_lds16(Bt + (size_t)(col0 + rw) * Kfull + k0 + kc * 8,
                          (bf16*)lB + cb * 8);
            }
        } else {
            // B tile fp32: 1024 chunks x 16B, XOR-swizzled (kc ^ (row&7))
#pragma unroll
            for (int r = 0; r < 4; ++r) {
                const int cb    = r * 256 + wave * 64;
                const int chunk = cb + lane;
                const int rw = chunk >> 3, kc = chunk & 7;
                const int kcs = kc ^ (rw & 7);
                gld_lds16(Bt + (size_t)(col0 + rw) * Kfull + k0 + kcs * 4,
                          (float*)lB + cb * 4);
            }
        }
        __syncthreads();
        bf16x8 af[4], bfr[4];
#pragma unroll
        for (int i = 0; i < 4; i++)
            af[i]  = *(const bf16x8*)(lA + (wm * 64 + i * 16 + lo) * 32 + hi * 8);
#pragma unroll
        for (int i = 0; i < 4; i++) {
            if constexpr (sizeof(WT) == 2) {
                bfr[i] = *(const bf16x8*)((const bf16*)lB +
                             (wn * 64 + i * 16 + lo) * 32 + hi * 8);
            } else {
                const float* base = (const float*)lB + (wn * 64 + i * 16 + lo) * 32;
                const int sw = lo & 7;
                const f32x4 u0 = *(const f32x4*)(base + (((hi * 2)     ^ sw) * 4));
                const f32x4 u1 = *(const f32x4*)(base + (((hi * 2 + 1) ^ sw) * 4));
                bf16x8 f;
#pragma unroll
                for (int e = 0; e < 4; e++) { f[e] = (bf16)u0[e]; f[4+e] = (bf16)u1[e]; }
                bfr[i] = f;
            }
        }
#pragma unroll
        for (int mi = 0; mi < 4; mi++)
#pragma unroll
            for (int ni = 0; ni < 4; ni++)
                acc[mi][ni] = __builtin_amdgcn_mfma_f32_16x16x32_bf16(
                    af[mi], bfr[ni], acc[mi][ni], 0, 0, 0);
        __syncthreads();
    }

    // epilogue: C/D layout col=lane&15, row=(lane>>4)*4+reg
    const float bscale = (blockIdx.z == 0) ? 1.0f : 0.0f;
#pragma unroll
    for (int mi = 0; mi < 4; mi++) {
#pragma unroll
        for (int ni = 0; ni < 4; ni++) {
            const int gcol = col0 + wn * 64 + ni * 16 + lo;
            const float bv = bias[gcol] * bscale;
#pragma unroll
            for (int r = 0; r < 4; r++) {
                const int grow = row0 + wm * 64 + mi * 16 + hi * 4 + r;
                float v = acc[mi][ni][r] + bv;
                if (MODE == 1) v = 0.5f * v * (1.0f + erff(v * 0.70710678118f));
                if (MODE == 2) {
                    atomicAdd(&resid[(size_t)grow * N + gcol], v);
                } else {
                    out[(size_t)grow * N + gcol] = (bf16)v;
                }
            }
        }
    }
}

// =====================================================================
// fp32 -> bf16 bulk convert (weights), 8 elems/lane
// =====================================================================
__global__ __launch_bounds__(256) void cvt_k(
    const float* __restrict__ src, bf16* __restrict__ dst)
{
    const int i = (blockIdx.x * 256 + threadIdx.x) * 8;
    const f32x4 a = *(const f32x4*)(src + i);
    const f32x4 b = *(const f32x4*)(src + i + 4);
    bf16x8 o;
#pragma unroll
    for (int e = 0; e < 4; e++) { o[e] = (bf16)a[e]; o[4 + e] = (bf16)b[e]; }
    *(bf16x8*)(dst + i) = o;
}

// =====================================================================
// LayerNorm: fp32 in [T,768] -> OutT out [T,768]; one wave per token
// =====================================================================
template<typename OutT>
__global__ __launch_bounds__(256) void ln_k(
    const float* __restrict__ x, const float* __restrict__ g,
    const float* __restrict__ b, OutT* __restrict__ out)
{
    const int wave = threadIdx.x >> 6, lane = threadIdx.x & 63;
    const int t = blockIdx.x * 4 + wave;
    const float* row = x + (size_t)t * C_;
    f32x4 v[3];
    float s = 0.f, ss = 0.f;
#pragma unroll
    for (int j = 0; j < 3; j++) {
        v[j] = *(const f32x4*)(row + (j * 64 + lane) * 4);
#pragma unroll
        for (int e = 0; e < 4; e++) { s += v[j][e]; ss += v[j][e] * v[j][e]; }
    }
#pragma unroll
    for (int off = 32; off > 0; off >>= 1) {
        s  += __shfl_xor(s, off);
        ss += __shfl_xor(ss, off);
    }
    const float mu  = s * (1.f / 768.f);
    const float var = ss * (1.f / 768.f) - mu * mu;
    const float rs  = rsqrtf(var + 1e-5f);
    OutT* orow = out + (size_t)t * C_;
#pragma unroll
    for (int j = 0; j < 3; j++) {
        const f32x4 gv = *(const f32x4*)(g + (j * 64 + lane) * 4);
        const f32x4 bv = *(const f32x4*)(b + (j * 64 + lane) * 4);
#pragma unroll
        for (int e = 0; e < 4; e++)
            orow[(j * 64 + lane) * 4 + e] = (OutT)((v[j][e] - mu) * rs * gv[e] + bv[e]);
    }
}

// =====================================================================
// x + pos_x (fp32) -> fp32 residual stream
// =====================================================================
__global__ __launch_bounds__(256) void addpos_k(
    const float* __restrict__ x, const float* __restrict__ p, float* __restrict__ o)
{
    const int i = (blockIdx.x * 256 + threadIdx.x) * 4;
    const f32x4 xv = *(const f32x4*)(x + i);
    const f32x4 pv = *(const f32x4*)(p + i);
    f32x4 ov;
#pragma unroll
    for (int e = 0; e < 4; e++) ov[e] = xv[e] + pv[e];
    *(f32x4*)(o + i) = ov;
}

// =====================================================================
// Flash attention: qkv bf16 [4096, 2304] -> out bf16 [4096, 768]
// block = (qtile of 64 rows, b*H+h); 4 waves, wave w owns q rows w*16..+16
// LDS rows padded to 72 bf16 (144 B) -> frag-read quad = (lo+hi)&7, ~free.
// V^T staged via transposed coalesced ushort loads (VMEM pipe, no scatter).
// 2 barriers per K-tile (lP is wave-private, needs no barrier).
// =====================================================================
#define SK_ 72
__global__ __launch_bounds__(256) void attn_k(
    const bf16* __restrict__ qkv, bf16* __restrict__ out)
{
    const int qt = blockIdx.x;          // 0..15
    const int bh = blockIdx.y;          // 0..47
    const int b = bh / H_, h = bh % H_;
    const int lane = threadIdx.x & 63, wave = threadIdx.x >> 6;
    const int lo = lane & 15, hi = lane >> 4;

    __shared__ __align__(16) bf16 lK[64 * SK_];       // [key][d]   padded
    __shared__ __align__(16) bf16 lV[64 * SK_];       // V^T [d][key] padded
    __shared__ __align__(16) bf16 lP[4][16 * SK_];    // per-wave P [q][key]

    const size_t tokbase = (size_t)b * N_;

    // persistent Q A-fragments: m=lo (q row), k = hi*8+j (+32 for qf1)
    const bf16* qptr = qkv + (tokbase + qt * 64 + wave * 16 + lo) * (3 * C_) + h * HD_;
    const bf16x8 qf0 = *(const bf16x8*)(qptr + hi * 8);
    const bf16x8 qf1 = *(const bf16x8*)(qptr + 32 + hi * 8);

    float m_r[4], l_r[4];
    f32x4 oacc[4];
#pragma unroll
    for (int r = 0; r < 4; r++) { m_r[r] = -1e30f; l_r[r] = 0.f; }
#pragma unroll
    for (int di = 0; di < 4; di++) oacc[di] = (f32x4){0.f, 0.f, 0.f, 0.f};

    for (int kt = 0; kt < 16; ++kt) {
        const int kb0 = kt * 64;
        // ---- K: vectorized [key][d] staging (quad=(key+dc)&7) ----
#pragma unroll
        for (int r = 0; r < 2; ++r) {
            const int chunk = r * 256 + threadIdx.x;     // 0..511
            const int key = chunk >> 3, dc = chunk & 7;
            const bf16* kp = qkv + (tokbase + kb0 + key) * (3 * C_) + C_ + h * HD_ + dc * 8;
            *(bf16x8*)(lK + key * SK_ + dc * 8) = *(const bf16x8*)kp;
        }
        // ---- V^T: transposed coalesced loads (lane d, 8 keys) ----
#pragma unroll
        for (int r = 0; r < 2; ++r) {
            const int chunk = r * 256 + threadIdx.x;     // 0..511
            const int d = chunk & 63, kg = chunk >> 6;   // kg 0..7
            const bf16* vp = qkv + (tokbase + kb0 + kg * 8) * (3 * C_)
                           + 2 * C_ + h * HD_ + d;
            bf16x8 tv;
#pragma unroll
            for (int i = 0; i < 8; i++) tv[i] = vp[(size_t)i * (3 * C_)];
            *(bf16x8*)(lV + d * SK_ + kg * 8) = tv;
        }
        __syncthreads();

        // ---- S = Q @ K^T (per wave: 16 q x 64 keys) ----
        f32x4 sacc[4];
#pragma unroll
        for (int kb = 0; kb < 4; kb++) {
            const bf16x8 b0 = *(const bf16x8*)(lK + (kb * 16 + lo) * SK_ + hi * 8);
            const bf16x8 b1 = *(const bf16x8*)(lK + (kb * 16 + lo) * SK_ + 32 + hi * 8);
            f32x4 a = (f32x4){0.f, 0.f, 0.f, 0.f};
            a = __builtin_amdgcn_mfma_f32_16x16x32_bf16(qf0, b0, a, 0, 0, 0);
            a = __builtin_amdgcn_mfma_f32_16x16x32_bf16(qf1, b1, a, 0, 0, 0);
            sacc[kb] = a;
        }

        // ---- online softmax (row r = q row hi*4+r; reduce over lo lanes) ----
        float tm[4], mn[4], alpha[4], ts[4], ps[4][4];
#pragma unroll
        for (int r = 0; r < 4; r++) {
            tm[r] = fmaxf(fmaxf(sacc[0][r], sacc[1][r]),
                          fmaxf(sacc[2][r], sacc[3][r])) * 0.125f;
#pragma unroll
            for (int off = 1; off < 16; off <<= 1)
                tm[r] = fmaxf(tm[r], __shfl_xor(tm[r], off));
            mn[r] = fmaxf(m_r[r], tm[r]);
            alpha[r] = __expf(m_r[r] - mn[r]);
            ts[r] = 0.f;
        }
#pragma unroll
        for (int kb = 0; kb < 4; kb++)
#pragma unroll
            for (int r = 0; r < 4; r++) {
                const float p = __expf(sacc[kb][r] * 0.125f - mn[r]);
                ps[kb][r] = p;
                ts[r] += p;
            }
#pragma unroll
        for (int r = 0; r < 4; r++) {
#pragma unroll
            for (int off = 1; off < 16; off <<= 1)
                ts[r] += __shfl_xor(ts[r], off);
            l_r[r] = l_r[r] * alpha[r] + ts[r];
            m_r[r] = mn[r];
        }
#pragma unroll
        for (int di = 0; di < 4; di++)
#pragma unroll
            for (int r = 0; r < 4; r++) oacc[di][r] *= alpha[r];

        // ---- P: C-layout -> wave-private LDS -> A-layout (no barrier) ----
#pragma unroll
        for (int kb = 0; kb < 4; kb++)
#pragma unroll
            for (int r = 0; r < 4; r++)
                lP[wave][(hi * 4 + r) * SK_ + kb * 16 + lo] = (bf16)ps[kb][r];

        const bf16x8 pa0 = *(const bf16x8*)(&lP[wave][lo * SK_ + hi * 8]);
        const bf16x8 pa1 = *(const bf16x8*)(&lP[wave][lo * SK_ + 32 + hi * 8]);
#pragma unroll
        for (int di = 0; di < 4; di++) {
            const bf16x8 v0 = *(const bf16x8*)(lV + (di * 16 + lo) * SK_ + hi * 8);
            const bf16x8 v1 = *(const bf16x8*)(lV + (di * 16 + lo) * SK_ + 32 + hi * 8);
            oacc[di] = __builtin_amdgcn_mfma_f32_16x16x32_bf16(pa0, v0, oacc[di], 0, 0, 0);
            oacc[di] = __builtin_amdgcn_mfma_f32_16x16x32_bf16(pa1, v1, oacc[di], 0, 0, 0);
        }
        __syncthreads();
    }

    // ---- epilogue: O / l ----
#pragma unroll
    for (int di = 0; di < 4; di++)
#pragma unroll
        for (int r = 0; r < 4; r++) {
            const size_t tok = tokbase + qt * 64 + wave * 16 + hi * 4 + r;
            out[tok * C_ + h * HD_ + di * 16 + lo] = (bf16)(oacc[di][r] / l_r[r]);
        }
}

// =====================================================================
extern "C" void kernel_launch(void* const* d_in, const int* in_sizes, int n_in,
                              void* d_out, int out_size, void* d_ws, size_t ws_size,
                              hipStream_t stream)
{
    const float* x      = (const float*)d_in[0];
    const float* pos_x  = (const float*)d_in[1];
    const float* qkv_w  = (const float*)d_in[2];
    const float* qkv_b  = (const float*)d_in[3];
    const float* proj_w = (const float*)d_in[4];
    const float* proj_b = (const float*)d_in[5];
    const float* fc1_w  = (const float*)d_in[6];
    const float* fc1_b  = (const float*)d_in[7];
    const float* fc2_w  = (const float*)d_in[8];
    const float* fc2_b  = (const float*)d_in[9];
    const float* ln1_g  = (const float*)d_in[10];
    const float* ln1_b  = (const float*)d_in[11];
    const float* ln2_g  = (const float*)d_in[12];
    const float* ln2_b  = (const float*)d_in[13];
    const float* nf_g   = (const float*)d_in[14];
    const float* nf_b   = (const float*)d_in[15];

    char* ws = (char*)d_ws;
    float* xres  = (float*)(ws);                         // 12,582,912 B
    bf16* hbuf   = (bf16*)(ws + 12582912);               //  6,291,456
    bf16* qkvbuf = (bf16*)(ws + 18874368);               // 18,874,368
    bf16* attno  = (bf16*)(ws + 37748736);               //  6,291,456
    bf16* hid    = (bf16*)(ws + 44040192);               // 25,165,824 (end 69,206,016)
    bf16* wq     = (bf16*)(ws + 69206016);               // 42,467,328
    bf16* wp     = (bf16*)(ws + 111673344);              // 14,155,776
    bf16* w1     = (bf16*)(ws + 125829120);              // 56,623,104
    bf16* w2     = (bf16*)(ws + 182452224);              // 56,623,104 (end 239,075,328)
    const bool usebf16 = ws_size >= (size_t)239075328;

    addpos_k<<<T_ * C_ / 4 / 256, 256, 0, stream>>>(x, pos_x, xres);

    if (usebf16) {
        cvt_k<<<D_ * 3 * C_ * C_ / 2048, 256, 0, stream>>>(qkv_w, wq);
        cvt_k<<<D_ * C_ * C_ / 2048, 256, 0, stream>>>(proj_w, wp);
        cvt_k<<<D_ * FF_ * C_ / 2048, 256, 0, stream>>>(fc1_w, w1);
        cvt_k<<<D_ * C_ * FF_ / 2048, 256, 0, stream>>>(fc2_w, w2);
    }

    for (int L = 0; L < D_; ++L) {
        ln_k<bf16><<<T_ / 4, 256, 0, stream>>>(xres, ln1_g + L * C_, ln1_b + L * C_, hbuf);
        if (usebf16) {
            gemm_bt<bf16,0><<<dim3(T_/128, (3*C_)/128, 1), 256, 0, stream>>>(
                hbuf, wq + (size_t)L * 3 * C_ * C_, qkv_b + (size_t)L * 3 * C_,
                qkvbuf, nullptr, T_, 3 * C_, C_, C_);
        } else {
            gemm_bt<float,0><<<dim3(T_/128, (3*C_)/128, 1), 256, 0, stream>>>(
                hbuf, qkv_w + (size_t)L * 3 * C_ * C_, qkv_b + (size_t)L * 3 * C_,
                qkvbuf, nullptr, T_, 3 * C_, C_, C_);
        }
        attn_k<<<dim3(N_ / 64, B_ * H_), 256, 0, stream>>>(qkvbuf, attno);
        if (usebf16) {
            gemm_bt<bf16,2><<<dim3(T_/128, C_/128, 2), 256, 0, stream>>>(
                attno, wp + (size_t)L * C_ * C_, proj_b + (size_t)L * C_,
                nullptr, xres, T_, C_, C_, C_ / 2);
        } else {
            gemm_bt<float,2><<<dim3(T_/128, C_/128, 2), 256, 0, stream>>>(
                attno, proj_w + (size_t)L * C_ * C_, proj_b + (size_t)L * C_,
                nullptr, xres, T_, C_, C_, C_ / 2);
        }
        ln_k<bf16><<<T_ / 4, 256, 0, stream>>>(xres, ln2_g + L * C_, ln2_b + L * C_, hbuf);
        if (usebf16) {
            gemm_bt<bf16,1><<<dim3(T_/128, FF_/128, 1), 256, 0, stream>>>(
                hbuf, w1 + (size_t)L * FF_ * C_, fc1_b + (size_t)L * FF_,
                hid, nullptr, T_, FF_, C_, C_);
            gemm_bt<bf16,2><<<dim3(T_/128, C_/128, 2), 256, 0, stream>>>(
                hid, w2 + (size_t)L * C_ * FF_, fc2_b + (size_t)L * C_,
                nullptr, xres, T_, C_, FF_, FF_ / 2);
        } else {
            gemm_bt<float,1><<<dim3(T_/128, FF_/128, 1), 256, 0, stream>>>(
                hbuf, fc1_w + (size_t)L * FF_ * C_, fc1_b + (size_t)L * FF_,
                hid, nullptr, T_, FF_, C_, C_);
            gemm_bt<float,2><<<dim3(T_/128, C_/128, 2), 256, 0, stream>>>(
                hid, fc2_w + (size_t)L * C_ * FF_, fc2_b + (size_t)L * C_,
                nullptr, xres, T_, C_, FF_, FF_ / 2);
        }
    }
    ln_k<float><<<T_ / 4, 256, 0, stream>>>(xres, nf_g, nf_b, (float*)d_out);
}